// Round 12
// baseline (138.646 us; speedup 1.0000x reference)
//
#include <hip/hip_runtime.h>
#include <hip/hip_bf16.h>

typedef unsigned int   u32;
typedef unsigned short u16;

typedef __attribute__((ext_vector_type(8))) short    sh8;
typedef __attribute__((ext_vector_type(4))) float    f32x4;
typedef __attribute__((ext_vector_type(8))) _Float16 f16x8;
typedef __attribute__((ext_vector_type(2))) _Float16 f16x2;
typedef __attribute__((ext_vector_type(2))) __fp16   fp16x2raw;

union F16x8 { f16x8 v; uint4 u; f16x2 p[4]; _Float16 h[8]; };
union F16x4u { uint2 u; _Float16 h[4]; };
union F16x2u { u32 u; _Float16 h[2]; };
union CvtU  { fp16x2raw r; f16x2 p; u32 u; };

__device__ __forceinline__ float b2f(u16 u) { union { u32 i; float f; } v; v.i = ((u32)u) << 16; return v.f; }
__device__ __forceinline__ u16   f2b(float f){
  union { float f; u32 i; } v; v.f = f;
  u32 u = v.i;
  u32 r = (u + 0x7fffu + ((u >> 16) & 1u)) >> 16;   // RNE
  return (u16)r;
}
// pack two f32 -> bf16x2 (RNE), lo half = a, hi half = b
__device__ __forceinline__ u32 pk2(float a, float b) {
  __hip_bfloat162 h2 = __float22bfloat162_rn(make_float2(a, b));
  union { __hip_bfloat162 h; u32 u; } v; v.h = h2; return v.u;
}
__device__ __forceinline__ f16x2 cvtpk(float a, float b) {
  CvtU c; c.r = __builtin_amdgcn_cvt_pkrtz(a, b); return c.p;
}
__device__ __forceinline__ u32 cvtpku(float a, float b) {
  CvtU c; c.r = __builtin_amdgcn_cvt_pkrtz(a, b); return c.u;
}

__device__ __forceinline__ f32x4 mfma16(uint4 a, uint4 b, f32x4 c) {
  union { uint4 u; sh8 s; } ua, ub;
  ua.u = a; ub.u = b;
  return __builtin_amdgcn_mfma_f32_16x16x32_bf16(ua.s, ub.s, c, 0, 0, 0);
}
__device__ __forceinline__ f32x4 mfma32h(f16x8 a, f16x8 b, f32x4 c) {
  return __builtin_amdgcn_mfma_f32_16x16x32_f16(a, b, c, 0, 0, 0);
}

// split 8 consecutive f32 (one lane's K-chunk) into bf16 hi/lo operand words
__device__ __forceinline__ void split8(float4 v0, float4 v1, uint4& hi, uint4& lo) {
  float a[8] = {v0.x, v0.y, v0.z, v0.w, v1.x, v1.y, v1.z, v1.w};
  u32 hw[4], lw[4];
#pragma unroll
  for (int t = 0; t < 4; t++) {
    u32 hp = pk2(a[2 * t], a[2 * t + 1]);
    float r0 = a[2 * t]     - __uint_as_float(hp << 16);
    float r1 = a[2 * t + 1] - __uint_as_float(hp & 0xffff0000u);
    hw[t] = hp;
    lw[t] = pk2(r0, r1);
  }
  hi = make_uint4(hw[0], hw[1], hw[2], hw[3]);
  lo = make_uint4(lw[0], lw[1], lw[2], lw[3]);
}

// packed f16 ReLU: max(x, +0) per half.  Bit-exact vs cvt(fmax(a,0)) for all
// inputs incl. -0 (v_pk_max_f16 returns src1=+0 when src0 <= +0).
__device__ __forceinline__ u32 pkmax0(u32 x, u32 zz) {
  u32 r;
  asm("v_pk_max_f16 %0, %1, %2" : "=v"(r) : "v"(x), "v"(zz));
  return r;
}

// ---------------------------------------------------------------------------
// gemm_mf2t: output projections, FULLY LDS-STAGED (R8 champion, verbatim).
// ---------------------------------------------------------------------------
__global__ void __launch_bounds__(256)
gemm_mf2t(const float* __restrict__ o1, const float* __restrict__ o2,
          const float* __restrict__ Wout1, const float* __restrict__ Wout2,
          float* __restrict__ out) {
  __shared__ __align__(16) uint4 AH[32 * 33];
  __shared__ __align__(16) uint4 AL[32 * 33];
  __shared__ __align__(16) uint4 BH[32 * 33];
  __shared__ __align__(16) uint4 BL[32 * 33];
  int t = threadIdx.x, L = t & 63, w = t >> 6;
  int cl = L & 15, q = L >> 4;
  int by = blockIdx.y, sel = by >> 5, mb = by & 31;
  int m0 = mb * 32, n0 = blockIdx.x * 32;
  const float* A  = sel ? o2 : o1;
  const float* Bw = sel ? Wout2 : Wout1;

  for (int e = t; e < 1024; e += 256) {
    int chunk = e & 31, row = e >> 5;
    const float* ap = A + (size_t)(m0 + row) * 256 + chunk * 8;
    float4 a0 = *(const float4*)ap;
    float4 a1 = *(const float4*)(ap + 4);
    uint4 hi, lo;
    split8(a0, a1, hi, lo);
    AH[chunk * 33 + row] = hi;
    AL[chunk * 33 + row] = lo;
    const float* bp = Bw + (size_t)(n0 + row) * 256 + chunk * 8;
    float4 b0 = *(const float4*)bp;
    float4 b1 = *(const float4*)(bp + 4);
    split8(b0, b1, hi, lo);
    BH[chunk * 33 + row] = hi;
    BL[chunk * 33 + row] = lo;
  }
  __syncthreads();

  int wm = w >> 1, wn = w & 1;
  int ma = 16 * wm + cl, na = 16 * wn + cl;
  f32x4 acc; acc[0] = 0.f; acc[1] = 0.f; acc[2] = 0.f; acc[3] = 0.f;
#pragma unroll
  for (int k0 = 0; k0 < 256; k0 += 32) {
    int cb = ((k0 >> 3) + q) * 33;
    uint4 ahi = AH[cb + ma];
    uint4 alo = AL[cb + ma];
    uint4 bhi = BH[cb + na];
    uint4 blo = BL[cb + na];
    acc = mfma16(ahi, bhi, acc);
    acc = mfma16(ahi, blo, acc);
    acc = mfma16(alo, bhi, acc);
  }
  float* C = out + (size_t)sel * 262144;
#pragma unroll
  for (int i = 0; i < 4; i++)
    C[(size_t)(m0 + 16 * wm + 4 * q + i) * 256 + n0 + 16 * wn + cl] = acc[i];
}

// ---------------------------------------------------------------------------
// gemm_mf_pack: QKV projections (R8 champion) + NEW mask bit-table duty.
// by==32, bx<8: W1/W2 packing (unchanged).  bx 8..15 (previously idle):
// build both orientations of the bit-packed mask table mbits:
//   mbits[0][b][row r][byte Lb] bit j = (mask[b][r][8Lb+j] != 0)
//   mbits[1][b][col c][byte i ] bit j = (mask[b][8i+j][c] != 0)
// (128 KB total; consumed by softmax_pv_mf; same !=0 tests -> identical
// masking decisions.)
// ---------------------------------------------------------------------------
__global__ void __launch_bounds__(256)
gemm_mf_pack(const float* __restrict__ x1, const float* __restrict__ Wqv1, u16* __restrict__ vhT1,
             const float* __restrict__ x2, const float* __restrict__ Wkv2, u16* __restrict__ vhT2,
             const float* __restrict__ W1, const float* __restrict__ W2,
             const int* __restrict__ mask, unsigned char* __restrict__ mbits,
             uint4* __restrict__ QQ4, uint4* __restrict__ KH4, uint4* __restrict__ KL4z,
             uint4* __restrict__ W1F8hi, uint4* __restrict__ W1F8lo,
             uint4* __restrict__ W2F8hi, uint4* __restrict__ W2F8lo) {
  __shared__ float Ld[4][16][17];
  __shared__ __align__(16) uint4 BH[32 * 33];
  __shared__ __align__(16) uint4 BL[32 * 33];
  int t = threadIdx.x, L = t & 63, w = t >> 6;
  int cl = L & 15, q = L >> 4;
  int by = blockIdx.y;

  if (by == 32) {                       // ---- W packing / mask bit-table ----
    if (blockIdx.x >= 8) {              // mask bit-tables (8 blocks, 2048 thr)
      int tid = (blockIdx.x - 8) * 256 + t;
      // orientation 0: row-major bits, coalesced 32B/lane reads
      for (int it = 0; it < 32; it++) {
        int e = it * 2048 + tid;
        int Lb = e & 63, row = (e >> 6) & 511, bb = e >> 15;
        const int* mr = mask + ((size_t)(bb * 512) + row) * 512 + 8 * Lb;
        uint4 m0 = *(const uint4*)mr;
        uint4 m1 = *(const uint4*)(mr + 4);
        u32 bits = (u32)(m0.x != 0)        | ((u32)(m0.y != 0) << 1)
                 | ((u32)(m0.z != 0) << 2) | ((u32)(m0.w != 0) << 3)
                 | ((u32)(m1.x != 0) << 4) | ((u32)(m1.y != 0) << 5)
                 | ((u32)(m1.z != 0) << 6) | ((u32)(m1.w != 0) << 7);
        mbits[(size_t)bb * 32768 + row * 64 + Lb] = (unsigned char)bits;
      }
      // orientation T: col-major bits; consecutive tids -> consecutive cols
      for (int it = 0; it < 32; it++) {
        int e = it * 2048 + tid;
        int col = e & 511, i = (e >> 9) & 63, bb = e >> 15;
        u32 bits = 0;
#pragma unroll
        for (int j = 0; j < 8; j++)
          bits |= (u32)(mask[((size_t)(bb * 512) + 8 * i + j) * 512 + col] != 0) << j;
        mbits[65536 + (size_t)bb * 32768 + col * 64 + i] = (unsigned char)bits;
      }
      return;
    }
    int tid = blockIdx.x * 256 + t;     // 0..2047
    if (tid < 1024) {
      int LL = tid & 63, nt = tid >> 6;
      int j = nt * 16 + (LL & 15), qq = LL >> 4;
      F16x8 hi, lo;
#pragma unroll
      for (int jj = 0; jj < 8; jj++) {
        float wv = W1[j * 32 + qq * 8 + jj];
        hi.h[jj] = (_Float16)wv;
        lo.h[jj] = (_Float16)(wv - (float)hi.h[jj]);
      }
      W1F8hi[tid] = hi.u;
      W1F8lo[tid] = lo.u;
    } else if (tid < 1536) {
      int t2 = tid - 1024;              // p*64 + L
      int LL = t2 & 63, p = t2 >> 6;
      int h = LL & 15, qq = LL >> 4;
      F16x8 hi, lo;
#pragma unroll
      for (int jj = 0; jj < 8; jj++) {
        int j = 32 * p + ((jj >> 2) << 4) + 4 * qq + (jj & 3);
        float wv = W2[h * 256 + j];
        hi.h[jj] = (_Float16)wv;
        lo.h[jj] = (_Float16)(wv - (float)hi.h[jj]);
      }
      W2F8hi[t2] = hi.u;
      W2F8lo[t2] = lo.u;
    }
    return;
  }

  int sel = by >> 4;
  const float* A  = sel ? x2 : x1;
  const float* Bw = sel ? Wkv2 : Wqv1;
  int m0 = (by & 15) * 64 + w * 16;
  int n0 = blockIdx.x * 32;             // 32-column block (2 tiles/wave)

  for (int e = t; e < 1024; e += 256) {
    int chunk = e & 31, row = e >> 5;
    const float* bp = Bw + (size_t)(n0 + row) * 256 + chunk * 8;
    float4 b0 = *(const float4*)bp;
    float4 b1 = *(const float4*)(bp + 4);
    uint4 hi, lo;
    split8(b0, b1, hi, lo);
    BH[chunk * 33 + row] = hi;
    BL[chunk * 33 + row] = lo;
  }
  __syncthreads();

  f32x4 acc0; acc0[0] = 0.f; acc0[1] = 0.f; acc0[2] = 0.f; acc0[3] = 0.f;
  f32x4 acc1 = acc0;
  const float* ar = A + (size_t)(m0 + cl) * 256 + 8 * q;

  for (int k0 = 0; k0 < 256; k0 += 32) {
    float4 av0 = *(const float4*)(ar + k0);
    float4 av1 = *(const float4*)(ar + k0 + 4);
    uint4 ahi, alo;
    split8(av0, av1, ahi, alo);
    int cb = ((k0 >> 3) + q) * 33;
    uint4 bhi0 = BH[cb + cl],      blo0 = BL[cb + cl];
    uint4 bhi1 = BH[cb + 16 + cl], blo1 = BL[cb + 16 + cl];
    acc0 = mfma16(ahi, bhi0, acc0);
    acc0 = mfma16(ahi, blo0, acc0);
    acc0 = mfma16(alo, bhi0, acc0);
    acc1 = mfma16(ahi, bhi1, acc1);
    acc1 = mfma16(ahi, blo1, acc1);
    acc1 = mfma16(alo, bhi1, acc1);
  }

  int b = m0 >> 9;
  int row = (m0 & 511) + cl;            // r (or c) index after transpose

#pragma unroll
  for (int ti = 0; ti < 2; ti++) {
    f32x4 acc = ti ? acc1 : acc0;
    int n0p = n0 + 16 * ti;

    if (n0p >= 256) {                   // ---- V half: TRANSPOSED f16 store ----
#pragma unroll
      for (int i = 0; i < 4; i++) Ld[w][cl][4 * q + i] = acc[i];
      if (q < 2) {
        float vt[8];
#pragma unroll
        for (int jj = 0; jj < 8; jj++) vt[jj] = Ld[w][cl][q * 8 + jj];
        uint4 o = make_uint4(cvtpku(vt[0], vt[1]), cvtpku(vt[2], vt[3]),
                             cvtpku(vt[4], vt[5]), cvtpku(vt[6], vt[7]));
        u16* vT = sel ? vhT2 : vhT1;
        *(uint4*)(vT + ((size_t)(b * 256) + (n0p - 256) + cl) * 512 + (m0 & 511) + 8 * q) = o;
      }
      continue;
    }

    // ---- Q/K half: per-wave 16x16 transpose, then fragment emit ----
#pragma unroll
    for (int i = 0; i < 4; i++) Ld[w][cl][4 * q + i] = acc[i];   // Ld[d][r_local]
    float v[8];
#pragma unroll
    for (int jj = 0; jj < 8; jj++) v[jj] = Ld[w][(q & 1) * 8 + jj][cl];

    int r = row;
    int h = n0p >> 4;                   // head = 2*bx + ti

    if (sel == 0) {                     // Q: x0.25 folded; q<2 hi, q>=2 lo
      u32 wv[4];
#pragma unroll
      for (int t2 = 0; t2 < 4; t2++) {
        float a  = v[2 * t2] * 0.25f, bb = v[2 * t2 + 1] * 0.25f;
        u32 hp = pk2(a, bb);
        if (q >= 2) {
          float r0 = a  - __uint_as_float(hp << 16);
          float r1 = bb - __uint_as_float(hp & 0xffff0000u);
          wv[t2] = pk2(r0, r1);
        } else wv[t2] = hp;
      }
      QQ4[((size_t)((b * 16 + h) * 4 + q) << 9) + r] = make_uint4(wv[0], wv[1], wv[2], wv[3]);
    } else {                            // K: hi + lo + zero slots
      u32 hw[4], lw[4];
#pragma unroll
      for (int t2 = 0; t2 < 4; t2++) {
        float a = v[2 * t2], bb = v[2 * t2 + 1];
        u32 hp = pk2(a, bb);
        float r0 = a  - __uint_as_float(hp << 16);
        float r1 = bb - __uint_as_float(hp & 0xffff0000u);
        hw[t2] = hp;
        lw[t2] = pk2(r0, r1);
      }
      if (q < 2) {
        KH4[((size_t)((b * 16 + h) * 2 + q) << 9) + r]       = make_uint4(hw[0], hw[1], hw[2], hw[3]);
        KL4z[((size_t)((b * 16 + h) * 4 + 2 + q) << 9) + r]  = make_uint4(0, 0, 0, 0);
      } else {
        KL4z[((size_t)((b * 16 + h) * 4 + (q - 2)) << 9) + r] = make_uint4(lw[0], lw[1], lw[2], lw[3]);
      }
    }
  }
}

// ---------------------------------------------------------------------------
// ms_mfma8c: R9 champion verbatim (XCD pairing bid%8 = rtile32%8; hoisted
// cost loads; depth-1 weight prefetch; packed-f16 ReLU; uint2 ms1 stores;
// ms2 epilogue restored -- R10/R11 layout experiments refuted).
// ---------------------------------------------------------------------------
__global__ void __launch_bounds__(256, 4)
ms_mfma8c(const uint4* __restrict__ QQ4, const uint4* __restrict__ KH4,
          const uint4* __restrict__ KL4z, const float* __restrict__ cost,
          const uint4* __restrict__ W1F8hi, const uint4* __restrict__ W1F8lo,
          const uint4* __restrict__ W2F8hi, const uint4* __restrict__ W2F8lo,
          u16* __restrict__ ms1, u16* __restrict__ ms2) {
  __shared__ __align__(16) u32 Dl[2 * 2176];   // per wave-pair [16r][8hp][17]
  int t = threadIdx.x, L = t & 63, w = t >> 6;
  int cl = L & 15, q = L >> 4;
  int b = blockIdx.z, c0 = blockIdx.y * 16;    // c-tile from Y
  int pairId = w >> 1, wl = w & 1;
  int r0a = blockIdx.x * 32 + pairId * 16;     // r-tile from X
  int r0  = r0a + wl * 8;                      // this wave's 8 output rows
  u32* D = Dl + pairId * 2176;

  f32x4 z; z[0] = 0.f; z[1] = 0.f; z[2] = 0.f; z[3] = 0.f;

  // ---- cost loads hoisted (consumed in phase A2) ----
  float cvh[8];
#pragma unroll
  for (int rr = 0; rr < 8; rr++)
    cvh[rr] = cost[((size_t)(b * 512) + r0 + rr) * 512 + c0 + cl];

  // ---- phase A: 4 head-pairs per wave (hp = wl*4 + i), full 16-row tile ----
#pragma unroll 2
  for (int hpi = 0; hpi < 4; hpi++) {
    int hp = wl * 4 + hpi;
    int h0 = 2 * hp, h1 = 2 * hp + 1;
    uint4 qa  = QQ4[((size_t)((b * 16 + h0) * 4 + q) << 9) + r0a + cl];
    uint4 qa2 = QQ4[((size_t)((b * 16 + h0) * 4 + (q & 1)) << 9) + r0a + cl];
    uint4 kb1 = KH4[((size_t)((b * 16 + h0) * 2 + (q & 1)) << 9) + c0 + cl];
    uint4 kb2 = KL4z[((size_t)((b * 16 + h0) * 4 + q) << 9) + c0 + cl];
    f32x4 d0 = mfma16(qa, kb1, z);
    d0 = mfma16(qa2, kb2, d0);
    uint4 qb  = QQ4[((size_t)((b * 16 + h1) * 4 + q) << 9) + r0a + cl];
    uint4 qb2 = QQ4[((size_t)((b * 16 + h1) * 4 + (q & 1)) << 9) + r0a + cl];
    uint4 kc1 = KH4[((size_t)((b * 16 + h1) * 2 + (q & 1)) << 9) + c0 + cl];
    uint4 kc2 = KL4z[((size_t)((b * 16 + h1) * 4 + q) << 9) + c0 + cl];
    f32x4 d1 = mfma16(qb, kc1, z);
    d1 = mfma16(qb2, kc2, d1);
#pragma unroll
    for (int i = 0; i < 4; i++)
      D[(4 * q + i) * 136 + hp * 17 + cl] = cvtpku(d0[i], d1[i]);
  }
  __syncthreads();

  // ---- phase A2: build X f16x8 fragments (once), kept in registers ----
  F16x8 xv[8];
#pragma unroll
  for (int rr = 0; rr < 8; rr++) {
    int rl = wl * 8 + rr;
    u32 ch = cvtpku(0.f, cvh[rr]);             // cost f16 in high half
    u32 ua = D[rl * 136 + (2 * q) * 17 + cl];
    u32 ub = D[rl * 136 + (2 * q + 1) * 17 + cl];
    xv[rr].u = make_uint4((ua & 0xffffu) | ch, (ua >> 16) | ch,
                          (ub & 0xffffu) | ch, (ub >> 16) | ch);
  }

  // ---- phase B: p-outer MLP, depth-1 weight prefetch, packed-f16 ReLU ----
  f32x4 acc2[8];
#pragma unroll
  for (int rr = 0; rr < 8; rr++) acc2[rr] = z;

  u32 zz = 0;
  asm volatile("" : "+v"(zz));                 // pin +0 in a VGPR

  F16x8 w1h0, w1h1, w2h, w2l;
  w1h0.u = W1F8hi[0 * 64 + L];
  w1h1.u = W1F8hi[1 * 64 + L];
  w2h.u  = W2F8hi[0 * 64 + L];
  w2l.u  = W2F8lo[0 * 64 + L];

#pragma unroll 1
  for (int p = 0; p < 8; p++) {
    int pn = (p + 1) & 7;                      // p=7 reloads p=0 (harmless)
    F16x8 nw0, nw1, n2h, n2l;
    nw0.u = W1F8hi[(2 * pn) * 64 + L];
    nw1.u = W1F8hi[(2 * pn + 1) * 64 + L];
    n2h.u = W2F8hi[pn * 64 + L];
    n2l.u = W2F8lo[pn * 64 + L];
#pragma unroll
    for (int rr = 0; rr < 8; rr++) {
      f32x4 a0 = mfma32h(w1h0.v, xv[rr].v, z);
      f32x4 a1 = mfma32h(w1h1.v, xv[rr].v, z);
      F16x8 hf;
      hf.u = make_uint4(pkmax0(cvtpku(a0[0], a0[1]), zz),
                        pkmax0(cvtpku(a0[2], a0[3]), zz),
                        pkmax0(cvtpku(a1[0], a1[1]), zz),
                        pkmax0(cvtpku(a1[2], a1[3]), zz));
      acc2[rr] = mfma32h(hf.v, w2h.v, acc2[rr]);
      acc2[rr] = mfma32h(hf.v, w2l.v, acc2[rr]);
    }
    w1h0 = nw0; w1h1 = nw1; w2h = n2h; w2l = n2l;
  }

  // ---- epilogue: lane (q,cl) holds MS[h=cl][c=c0+4q+i][r0..r0+7] ----
  u32* ms1u = (u32*)ms1;
#pragma unroll
  for (int rr = 0; rr < 8; rr++) {
    size_t base = ((size_t)(b * 16 + cl) * 512 + (r0 + rr)) * 256 + (c0 >> 1) + q * 2;
    *(uint2*)&ms1u[base] = make_uint2(pk2(acc2[rr][0], acc2[rr][1]),
                                      pk2(acc2[rr][2], acc2[rr][3]));
  }
  u32* ms2u = (u32*)ms2;
#pragma unroll
  for (int i = 0; i < 4; i++) {
    int c = c0 + 4 * q + i;
    u32 o[4];
#pragma unroll
    for (int j = 0; j < 4; j++)
      o[j] = pk2(acc2[2 * j][i], acc2[2 * j + 1][i]);
    size_t base2 = ((size_t)(b * 16 + cl) * 512 + c) * 256 + (r0 >> 1);
    *(uint4*)&ms2u[base2] = make_uint4(o[0], o[1], o[2], o[3]);
  }
}

// ---------------------------------------------------------------------------
// softmax_pv_mf: softmax + PV via MFMA (R9 champion structure).  Mask now
// comes from the precomputed bit-tables: lane L loads bytes
// mbits[dir][b][fix0+f][L] (one coalesced 64B line per f) -- replaces the
// per-block mask rebuild, its LDS staging, and the mask __syncthreads()
// (remaining LDS is wave-private).  Masking decisions bit-identical.
// ---------------------------------------------------------------------------
__global__ void __launch_bounds__(256, 4)
softmax_pv_mf(const u16* __restrict__ ms1s, const u16* __restrict__ ms2s,
              const unsigned char* __restrict__ mbits,
              const u16* __restrict__ vhT1, const u16* __restrict__ vhT2,
              float* __restrict__ o1, float* __restrict__ o2) {
  __shared__ __align__(16) char pbufc[4][8192];     // per-wave P, swizzled
  __shared__ float sden[4][8];
  int t = threadIdx.x, L = t & 63, w = t >> 6;
  int cl = L & 15, q = L >> 4;
  int bx = blockIdx.x;
  int u  = (bx & 7) + 8 * ((bx >> 3) & 1);   // fix-tile32 (0..15)
  int v  = (bx >> 4) & 3;                    // 8-fix chunk  (0..3)
  int hq = bx >> 6;                          // head quad    (0..3)
  int rt = u * 4 + v;
  int b = blockIdx.y, dir = blockIdx.z;
  int fix0 = rt * 8, h = hq * 4 + w;
  const u16* ms = dir ? ms2s : ms1s;

  // ---- mask bytes from the precomputed bit-table (coalesced) ----
  const unsigned char* mbp = mbits + (size_t)dir * 65536 + (size_t)b * 32768 + fix0 * 64;
  u32 mbv[8];
#pragma unroll
  for (int f = 0; f < 8; f++) mbv[f] = mbp[f * 64 + L];

  // ---- phase 1: softmax over c for 8 fixes of head h ----
  const u16* msbase = ms + ((size_t)((b * 16 + h) * 512) + fix0) * 512 + 8 * L;
  uint4 pre[8];
#pragma unroll
  for (int f = 0; f < 8; f++) pre[f] = *(const uint4*)(msbase + f * 512);

  char* pb = pbufc[w];
#pragma unroll
  for (int f = 0; f < 8; f++) {
    u32 uw[4] = {pre[f].x, pre[f].y, pre[f].z, pre[f].w};
    float lg[8];
#pragma unroll
    for (int j = 0; j < 4; j++) {
      lg[2 * j]     = __uint_as_float(uw[j] << 16);
      lg[2 * j + 1] = __uint_as_float(uw[j] & 0xffff0000u);
    }
    u32 mb = mbv[f];
    bool um = (__ballot(mb != 0) != 0ULL);   // fully-masked row => unmask all
    u32 eff = um ? mb : 0xffu;
    float mx = -3.4e38f;
#pragma unroll
    for (int j = 0; j < 8; j++)
      mx = fmaxf(mx, ((eff >> j) & 1) ? lg[j] : -3.4e38f);
    for (int off = 32; off; off >>= 1) mx = fmaxf(mx, __shfl_xor(mx, off));
    float s = 0.f; u32 pw[4];
#pragma unroll
    for (int j = 0; j < 4; j++) {
      float p0 = ((eff >> (2 * j)) & 1)     ? __expf(lg[2 * j]     - mx) : 0.f;
      float p1 = ((eff >> (2 * j + 1)) & 1) ? __expf(lg[2 * j + 1] - mx) : 0.f;
      s += p0 + p1;
      pw[j] = cvtpku(p0, p1);
    }
    for (int off = 32; off; off >>= 1) s += __shfl_xor(s, off);
    if (L == 0) sden[w][f] = s;
    *(uint4*)(pb + f * 1024 + ((16 * L) ^ (f << 4))) = make_uint4(pw[0], pw[1], pw[2], pw[3]);
  }

  // ---- phase 2: PV via MFMA chain over K=512 ----
  const u16* vT = (dir ? vhT1 : vhT2) + ((size_t)(b * 256 + h * 16 + cl) * 512) + 8 * q;
  f32x4 accA; accA[0] = 0.f; accA[1] = 0.f; accA[2] = 0.f; accA[3] = 0.f;
  f32x4 accB = accA;
  int ar = (cl & 7);
#pragma unroll
  for (int kk = 0; kk < 16; kk++) {
    F16x8 pa, vb;
    pa.u = *(const uint4*)(pb + ar * 1024 + (((kk << 6) + (q << 4)) ^ (ar << 4)));
    vb.u = *(const uint4*)(vT + (kk << 5));
    if (kk & 1) accB = mfma32h(pa.v, vb.v, accB);
    else        accA = mfma32h(pa.v, vb.v, accA);
  }

  if (q < 2) {
    float* obuf = dir ? o2 : o1;
#pragma unroll
    for (int i = 0; i < 4; i++) {
      int f = 4 * q + i;
      float inv = 1.f / sden[w][f];
      obuf[((size_t)(b * 512) + fix0 + f) * 256 + h * 16 + cl] = (accA[i] + accB[i]) * inv;
    }
  }
}

// ---------------------------------------------------------------------------
extern "C" void kernel_launch(void* const* d_in, const int* in_sizes, int n_in,
                              void* d_out, int out_size, void* d_ws, size_t ws_size,
                              hipStream_t stream) {
  const float* x1    = (const float*)d_in[0];
  const float* x2    = (const float*)d_in[1];
  const int*   attn  = (const int*)d_in[2];
  const float* cost  = (const float*)d_in[3];
  const float* Wqv1  = (const float*)d_in[4];
  const float* Wkv2  = (const float*)d_in[5];
  const float* W1    = (const float*)d_in[6];
  const float* W2    = (const float*)d_in[7];
  const float* Wout1 = (const float*)d_in[8];
  const float* Wout2 = (const float*)d_in[9];
  float* out = (float*)d_out;

  char* ws = (char*)d_ws;
  uint4* W1F8hi = (uint4*)(ws);                              // 16 KB
  uint4* W1F8lo = (uint4*)(ws + (16 << 10));                 // 16 KB
  uint4* W2F8hi = (uint4*)(ws + (32 << 10));                 //  8 KB
  uint4* W2F8lo = (uint4*)(ws + (40 << 10));                 //  8 KB
  u16*   vhT1 = (u16*)(ws + (64 << 10));                     // 512 KB [b][256 ch][512 r] f16 (v1^T)
  u16*   vhT2 = (u16*)(ws + (64 << 10) + (512 << 10));       // 512 KB [b][256 ch][512 c] f16 (v2^T)
  u16*   ms1 = (u16*)(ws + (64 << 10) + (4 << 20));          //  16 MB [b][h][r][c]
  u16*   ms2 = (u16*)(ws + (64 << 10) + (20 << 20));         //  16 MB [b][h][c][r]
  char*  tail= (ws + (64 << 10) + (36 << 20));
  uint4* QQ4  = (uint4*)(tail);                              //   1 MB
  uint4* KH4  = (uint4*)(tail + (1 << 20));                  // 0.5 MB
  uint4* KL4z = (uint4*)(tail + (1 << 20) + (512 << 10));    //   1 MB
  float* o1  = (float*)(tail + (3 << 20));                   //   1 MB [b][r][256]
  float* o2  = (float*)(tail + (4 << 20));                   //   1 MB [b][c][256]
  unsigned char* mbits = (unsigned char*)(tail + (5 << 20)); // 128 KB [2][2][512][64]

  gemm_mf_pack<<<dim3(16, 33), 256, 0, stream>>>(x1, Wqv1, vhT1, x2, Wkv2, vhT2,
                                                 W1, W2, attn, mbits, QQ4, KH4, KL4z,
                                                 W1F8hi, W1F8lo, W2F8hi, W2F8lo);

  ms_mfma8c<<<dim3(16, 32, 2), 256, 0, stream>>>(QQ4, KH4, KL4z, cost,
                                                 W1F8hi, W1F8lo, W2F8hi, W2F8lo, ms1, ms2);

  softmax_pv_mf<<<dim3(256, 2, 2), 256, 0, stream>>>(ms1, ms2, mbits, vhT1, vhT2, o1, o2);

  gemm_mf2t<<<dim3(8, 64), 256, 0, stream>>>(o1, o2, Wout1, Wout2, out);
}

// Round 13
// 130.074 us; speedup vs baseline: 1.0659x; 1.0659x over previous
//
#include <hip/hip_runtime.h>
#include <hip/hip_bf16.h>

typedef unsigned int   u32;
typedef unsigned short u16;

typedef __attribute__((ext_vector_type(8))) short    sh8;
typedef __attribute__((ext_vector_type(4))) float    f32x4;
typedef __attribute__((ext_vector_type(8))) _Float16 f16x8;
typedef __attribute__((ext_vector_type(2))) _Float16 f16x2;
typedef __attribute__((ext_vector_type(2))) __fp16   fp16x2raw;

union F16x8 { f16x8 v; uint4 u; f16x2 p[4]; _Float16 h[8]; };
union F16x4u { uint2 u; _Float16 h[4]; };
union F16x2u { u32 u; _Float16 h[2]; };
union CvtU  { fp16x2raw r; f16x2 p; u32 u; };

__device__ __forceinline__ float b2f(u16 u) { union { u32 i; float f; } v; v.i = ((u32)u) << 16; return v.f; }
__device__ __forceinline__ u16   f2b(float f){
  union { float f; u32 i; } v; v.f = f;
  u32 u = v.i;
  u32 r = (u + 0x7fffu + ((u >> 16) & 1u)) >> 16;   // RNE
  return (u16)r;
}
// pack two f32 -> bf16x2 (RNE), lo half = a, hi half = b
__device__ __forceinline__ u32 pk2(float a, float b) {
  __hip_bfloat162 h2 = __float22bfloat162_rn(make_float2(a, b));
  union { __hip_bfloat162 h; u32 u; } v; v.h = h2; return v.u;
}
__device__ __forceinline__ f16x2 cvtpk(float a, float b) {
  CvtU c; c.r = __builtin_amdgcn_cvt_pkrtz(a, b); return c.p;
}
__device__ __forceinline__ u32 cvtpku(float a, float b) {
  CvtU c; c.r = __builtin_amdgcn_cvt_pkrtz(a, b); return c.u;
}

__device__ __forceinline__ f32x4 mfma16(uint4 a, uint4 b, f32x4 c) {
  union { uint4 u; sh8 s; } ua, ub;
  ua.u = a; ub.u = b;
  return __builtin_amdgcn_mfma_f32_16x16x32_bf16(ua.s, ub.s, c, 0, 0, 0);
}
__device__ __forceinline__ f32x4 mfma32h(f16x8 a, f16x8 b, f32x4 c) {
  return __builtin_amdgcn_mfma_f32_16x16x32_f16(a, b, c, 0, 0, 0);
}

// split 8 consecutive f32 (one lane's K-chunk) into bf16 hi/lo operand words
__device__ __forceinline__ void split8(float4 v0, float4 v1, uint4& hi, uint4& lo) {
  float a[8] = {v0.x, v0.y, v0.z, v0.w, v1.x, v1.y, v1.z, v1.w};
  u32 hw[4], lw[4];
#pragma unroll
  for (int t = 0; t < 4; t++) {
    u32 hp = pk2(a[2 * t], a[2 * t + 1]);
    float r0 = a[2 * t]     - __uint_as_float(hp << 16);
    float r1 = a[2 * t + 1] - __uint_as_float(hp & 0xffff0000u);
    hw[t] = hp;
    lw[t] = pk2(r0, r1);
  }
  hi = make_uint4(hw[0], hw[1], hw[2], hw[3]);
  lo = make_uint4(lw[0], lw[1], lw[2], lw[3]);
}

// packed f16 ReLU: max(x, +0) per half.  Bit-exact vs cvt(fmax(a,0)) for all
// inputs incl. -0 (v_pk_max_f16 returns src1=+0 when src0 <= +0).
__device__ __forceinline__ u32 pkmax0(u32 x, u32 zz) {
  u32 r;
  asm("v_pk_max_f16 %0, %1, %2" : "=v"(r) : "v"(x), "v"(zz));
  return r;
}

// ---------------------------------------------------------------------------
// gemm_mf2t: output projections, FULLY LDS-STAGED (R8 champion, verbatim).
// ---------------------------------------------------------------------------
__global__ void __launch_bounds__(256)
gemm_mf2t(const float* __restrict__ o1, const float* __restrict__ o2,
          const float* __restrict__ Wout1, const float* __restrict__ Wout2,
          float* __restrict__ out) {
  __shared__ __align__(16) uint4 AH[32 * 33];
  __shared__ __align__(16) uint4 AL[32 * 33];
  __shared__ __align__(16) uint4 BH[32 * 33];
  __shared__ __align__(16) uint4 BL[32 * 33];
  int t = threadIdx.x, L = t & 63, w = t >> 6;
  int cl = L & 15, q = L >> 4;
  int by = blockIdx.y, sel = by >> 5, mb = by & 31;
  int m0 = mb * 32, n0 = blockIdx.x * 32;
  const float* A  = sel ? o2 : o1;
  const float* Bw = sel ? Wout2 : Wout1;

  for (int e = t; e < 1024; e += 256) {
    int chunk = e & 31, row = e >> 5;
    const float* ap = A + (size_t)(m0 + row) * 256 + chunk * 8;
    float4 a0 = *(const float4*)ap;
    float4 a1 = *(const float4*)(ap + 4);
    uint4 hi, lo;
    split8(a0, a1, hi, lo);
    AH[chunk * 33 + row] = hi;
    AL[chunk * 33 + row] = lo;
    const float* bp = Bw + (size_t)(n0 + row) * 256 + chunk * 8;
    float4 b0 = *(const float4*)bp;
    float4 b1 = *(const float4*)(bp + 4);
    split8(b0, b1, hi, lo);
    BH[chunk * 33 + row] = hi;
    BL[chunk * 33 + row] = lo;
  }
  __syncthreads();

  int wm = w >> 1, wn = w & 1;
  int ma = 16 * wm + cl, na = 16 * wn + cl;
  f32x4 acc; acc[0] = 0.f; acc[1] = 0.f; acc[2] = 0.f; acc[3] = 0.f;
#pragma unroll
  for (int k0 = 0; k0 < 256; k0 += 32) {
    int cb = ((k0 >> 3) + q) * 33;
    uint4 ahi = AH[cb + ma];
    uint4 alo = AL[cb + ma];
    uint4 bhi = BH[cb + na];
    uint4 blo = BL[cb + na];
    acc = mfma16(ahi, bhi, acc);
    acc = mfma16(ahi, blo, acc);
    acc = mfma16(alo, bhi, acc);
  }
  float* C = out + (size_t)sel * 262144;
#pragma unroll
  for (int i = 0; i < 4; i++)
    C[(size_t)(m0 + 16 * wm + 4 * q + i) * 256 + n0 + 16 * wn + cl] = acc[i];
}

// ---------------------------------------------------------------------------
// gemm_mf_pack: QKV projections (R8 champion, verbatim: 2 n-tiles/wave,
// cooperative 32-col B stage, grid (16,33)).
// ---------------------------------------------------------------------------
__global__ void __launch_bounds__(256)
gemm_mf_pack(const float* __restrict__ x1, const float* __restrict__ Wqv1, u16* __restrict__ vhT1,
             const float* __restrict__ x2, const float* __restrict__ Wkv2, u16* __restrict__ vhT2,
             const float* __restrict__ W1, const float* __restrict__ W2,
             uint4* __restrict__ QQ4, uint4* __restrict__ KH4, uint4* __restrict__ KL4z,
             uint4* __restrict__ W1F8hi, uint4* __restrict__ W1F8lo,
             uint4* __restrict__ W2F8hi, uint4* __restrict__ W2F8lo) {
  __shared__ float Ld[4][16][17];
  __shared__ __align__(16) uint4 BH[32 * 33];
  __shared__ __align__(16) uint4 BL[32 * 33];
  int t = threadIdx.x, L = t & 63, w = t >> 6;
  int cl = L & 15, q = L >> 4;
  int by = blockIdx.y;

  if (by == 32) {                       // ---- W packing blocks ----
    if (blockIdx.x >= 8) return;
    int tid = blockIdx.x * 256 + t;     // 0..2047
    if (tid < 1024) {
      int LL = tid & 63, nt = tid >> 6;
      int j = nt * 16 + (LL & 15), qq = LL >> 4;
      F16x8 hi, lo;
#pragma unroll
      for (int jj = 0; jj < 8; jj++) {
        float wv = W1[j * 32 + qq * 8 + jj];
        hi.h[jj] = (_Float16)wv;
        lo.h[jj] = (_Float16)(wv - (float)hi.h[jj]);
      }
      W1F8hi[tid] = hi.u;
      W1F8lo[tid] = lo.u;
    } else if (tid < 1536) {
      int t2 = tid - 1024;              // p*64 + L
      int LL = t2 & 63, p = t2 >> 6;
      int h = LL & 15, qq = LL >> 4;
      F16x8 hi, lo;
#pragma unroll
      for (int jj = 0; jj < 8; jj++) {
        int j = 32 * p + ((jj >> 2) << 4) + 4 * qq + (jj & 3);
        float wv = W2[h * 256 + j];
        hi.h[jj] = (_Float16)wv;
        lo.h[jj] = (_Float16)(wv - (float)hi.h[jj]);
      }
      W2F8hi[t2] = hi.u;
      W2F8lo[t2] = lo.u;
    }
    return;
  }

  int sel = by >> 4;
  const float* A  = sel ? x2 : x1;
  const float* Bw = sel ? Wkv2 : Wqv1;
  int m0 = (by & 15) * 64 + w * 16;
  int n0 = blockIdx.x * 32;             // 32-column block (2 tiles/wave)

  for (int e = t; e < 1024; e += 256) {
    int chunk = e & 31, row = e >> 5;
    const float* bp = Bw + (size_t)(n0 + row) * 256 + chunk * 8;
    float4 b0 = *(const float4*)bp;
    float4 b1 = *(const float4*)(bp + 4);
    uint4 hi, lo;
    split8(b0, b1, hi, lo);
    BH[chunk * 33 + row] = hi;
    BL[chunk * 33 + row] = lo;
  }
  __syncthreads();

  f32x4 acc0; acc0[0] = 0.f; acc0[1] = 0.f; acc0[2] = 0.f; acc0[3] = 0.f;
  f32x4 acc1 = acc0;
  const float* ar = A + (size_t)(m0 + cl) * 256 + 8 * q;

  for (int k0 = 0; k0 < 256; k0 += 32) {
    float4 av0 = *(const float4*)(ar + k0);
    float4 av1 = *(const float4*)(ar + k0 + 4);
    uint4 ahi, alo;
    split8(av0, av1, ahi, alo);
    int cb = ((k0 >> 3) + q) * 33;
    uint4 bhi0 = BH[cb + cl],      blo0 = BL[cb + cl];
    uint4 bhi1 = BH[cb + 16 + cl], blo1 = BL[cb + 16 + cl];
    acc0 = mfma16(ahi, bhi0, acc0);
    acc0 = mfma16(ahi, blo0, acc0);
    acc0 = mfma16(alo, bhi0, acc0);
    acc1 = mfma16(ahi, bhi1, acc1);
    acc1 = mfma16(ahi, blo1, acc1);
    acc1 = mfma16(alo, bhi1, acc1);
  }

  int b = m0 >> 9;
  int row = (m0 & 511) + cl;            // r (or c) index after transpose

#pragma unroll
  for (int ti = 0; ti < 2; ti++) {
    f32x4 acc = ti ? acc1 : acc0;
    int n0p = n0 + 16 * ti;

    if (n0p >= 256) {                   // ---- V half: TRANSPOSED f16 store ----
#pragma unroll
      for (int i = 0; i < 4; i++) Ld[w][cl][4 * q + i] = acc[i];
      if (q < 2) {
        float vt[8];
#pragma unroll
        for (int jj = 0; jj < 8; jj++) vt[jj] = Ld[w][cl][q * 8 + jj];
        uint4 o = make_uint4(cvtpku(vt[0], vt[1]), cvtpku(vt[2], vt[3]),
                             cvtpku(vt[4], vt[5]), cvtpku(vt[6], vt[7]));
        u16* vT = sel ? vhT2 : vhT1;
        *(uint4*)(vT + ((size_t)(b * 256) + (n0p - 256) + cl) * 512 + (m0 & 511) + 8 * q) = o;
      }
      continue;
    }

    // ---- Q/K half: per-wave 16x16 transpose, then fragment emit ----
#pragma unroll
    for (int i = 0; i < 4; i++) Ld[w][cl][4 * q + i] = acc[i];   // Ld[d][r_local]
    float v[8];
#pragma unroll
    for (int jj = 0; jj < 8; jj++) v[jj] = Ld[w][(q & 1) * 8 + jj][cl];

    int r = row;
    int h = n0p >> 4;                   // head = 2*bx + ti

    if (sel == 0) {                     // Q: x0.25 folded; q<2 hi, q>=2 lo
      u32 wv[4];
#pragma unroll
      for (int t2 = 0; t2 < 4; t2++) {
        float a  = v[2 * t2] * 0.25f, bb = v[2 * t2 + 1] * 0.25f;
        u32 hp = pk2(a, bb);
        if (q >= 2) {
          float r0 = a  - __uint_as_float(hp << 16);
          float r1 = bb - __uint_as_float(hp & 0xffff0000u);
          wv[t2] = pk2(r0, r1);
        } else wv[t2] = hp;
      }
      QQ4[((size_t)((b * 16 + h) * 4 + q) << 9) + r] = make_uint4(wv[0], wv[1], wv[2], wv[3]);
    } else {                            // K: hi + lo + zero slots
      u32 hw[4], lw[4];
#pragma unroll
      for (int t2 = 0; t2 < 4; t2++) {
        float a = v[2 * t2], bb = v[2 * t2 + 1];
        u32 hp = pk2(a, bb);
        float r0 = a  - __uint_as_float(hp << 16);
        float r1 = bb - __uint_as_float(hp & 0xffff0000u);
        hw[t2] = hp;
        lw[t2] = pk2(r0, r1);
      }
      if (q < 2) {
        KH4[((size_t)((b * 16 + h) * 2 + q) << 9) + r]       = make_uint4(hw[0], hw[1], hw[2], hw[3]);
        KL4z[((size_t)((b * 16 + h) * 4 + 2 + q) << 9) + r]  = make_uint4(0, 0, 0, 0);
      } else {
        KL4z[((size_t)((b * 16 + h) * 4 + (q - 2)) << 9) + r] = make_uint4(lw[0], lw[1], lw[2], lw[3]);
      }
    }
  }
}

// ---------------------------------------------------------------------------
// ms_mfma8c: R9 champion verbatim (XCD pairing bid%8 = rtile32%8; hoisted
// cost loads; depth-1 weight prefetch; packed-f16 ReLU; uint2 ms1 stores;
// dual ms1/ms2 epilogue -- R10/R11/R12 alternatives all refuted).
// ---------------------------------------------------------------------------
__global__ void __launch_bounds__(256, 4)
ms_mfma8c(const uint4* __restrict__ QQ4, const uint4* __restrict__ KH4,
          const uint4* __restrict__ KL4z, const float* __restrict__ cost,
          const uint4* __restrict__ W1F8hi, const uint4* __restrict__ W1F8lo,
          const uint4* __restrict__ W2F8hi, const uint4* __restrict__ W2F8lo,
          u16* __restrict__ ms1, u16* __restrict__ ms2) {
  __shared__ __align__(16) u32 Dl[2 * 2176];   // per wave-pair [16r][8hp][17]
  int t = threadIdx.x, L = t & 63, w = t >> 6;
  int cl = L & 15, q = L >> 4;
  int b = blockIdx.z, c0 = blockIdx.y * 16;    // c-tile from Y
  int pairId = w >> 1, wl = w & 1;
  int r0a = blockIdx.x * 32 + pairId * 16;     // r-tile from X
  int r0  = r0a + wl * 8;                      // this wave's 8 output rows
  u32* D = Dl + pairId * 2176;

  f32x4 z; z[0] = 0.f; z[1] = 0.f; z[2] = 0.f; z[3] = 0.f;

  // ---- cost loads hoisted (consumed in phase A2) ----
  float cvh[8];
#pragma unroll
  for (int rr = 0; rr < 8; rr++)
    cvh[rr] = cost[((size_t)(b * 512) + r0 + rr) * 512 + c0 + cl];

  // ---- phase A: 4 head-pairs per wave (hp = wl*4 + i), full 16-row tile ----
#pragma unroll 2
  for (int hpi = 0; hpi < 4; hpi++) {
    int hp = wl * 4 + hpi;
    int h0 = 2 * hp, h1 = 2 * hp + 1;
    uint4 qa  = QQ4[((size_t)((b * 16 + h0) * 4 + q) << 9) + r0a + cl];
    uint4 qa2 = QQ4[((size_t)((b * 16 + h0) * 4 + (q & 1)) << 9) + r0a + cl];
    uint4 kb1 = KH4[((size_t)((b * 16 + h0) * 2 + (q & 1)) << 9) + c0 + cl];
    uint4 kb2 = KL4z[((size_t)((b * 16 + h0) * 4 + q) << 9) + c0 + cl];
    f32x4 d0 = mfma16(qa, kb1, z);
    d0 = mfma16(qa2, kb2, d0);
    uint4 qb  = QQ4[((size_t)((b * 16 + h1) * 4 + q) << 9) + r0a + cl];
    uint4 qb2 = QQ4[((size_t)((b * 16 + h1) * 4 + (q & 1)) << 9) + r0a + cl];
    uint4 kc1 = KH4[((size_t)((b * 16 + h1) * 2 + (q & 1)) << 9) + c0 + cl];
    uint4 kc2 = KL4z[((size_t)((b * 16 + h1) * 4 + q) << 9) + c0 + cl];
    f32x4 d1 = mfma16(qb, kc1, z);
    d1 = mfma16(qb2, kc2, d1);
#pragma unroll
    for (int i = 0; i < 4; i++)
      D[(4 * q + i) * 136 + hp * 17 + cl] = cvtpku(d0[i], d1[i]);
  }
  __syncthreads();

  // ---- phase A2: build X f16x8 fragments (once), kept in registers ----
  F16x8 xv[8];
#pragma unroll
  for (int rr = 0; rr < 8; rr++) {
    int rl = wl * 8 + rr;
    u32 ch = cvtpku(0.f, cvh[rr]);             // cost f16 in high half
    u32 ua = D[rl * 136 + (2 * q) * 17 + cl];
    u32 ub = D[rl * 136 + (2 * q + 1) * 17 + cl];
    xv[rr].u = make_uint4((ua & 0xffffu) | ch, (ua >> 16) | ch,
                          (ub & 0xffffu) | ch, (ub >> 16) | ch);
  }

  // ---- phase B: p-outer MLP, depth-1 weight prefetch, packed-f16 ReLU ----
  f32x4 acc2[8];
#pragma unroll
  for (int rr = 0; rr < 8; rr++) acc2[rr] = z;

  u32 zz = 0;
  asm volatile("" : "+v"(zz));                 // pin +0 in a VGPR

  F16x8 w1h0, w1h1, w2h, w2l;
  w1h0.u = W1F8hi[0 * 64 + L];
  w1h1.u = W1F8hi[1 * 64 + L];
  w2h.u  = W2F8hi[0 * 64 + L];
  w2l.u  = W2F8lo[0 * 64 + L];

#pragma unroll 1
  for (int p = 0; p < 8; p++) {
    int pn = (p + 1) & 7;                      // p=7 reloads p=0 (harmless)
    F16x8 nw0, nw1, n2h, n2l;
    nw0.u = W1F8hi[(2 * pn) * 64 + L];
    nw1.u = W1F8hi[(2 * pn + 1) * 64 + L];
    n2h.u = W2F8hi[pn * 64 + L];
    n2l.u = W2F8lo[pn * 64 + L];
#pragma unroll
    for (int rr = 0; rr < 8; rr++) {
      f32x4 a0 = mfma32h(w1h0.v, xv[rr].v, z);
      f32x4 a1 = mfma32h(w1h1.v, xv[rr].v, z);
      F16x8 hf;
      hf.u = make_uint4(pkmax0(cvtpku(a0[0], a0[1]), zz),
                        pkmax0(cvtpku(a0[2], a0[3]), zz),
                        pkmax0(cvtpku(a1[0], a1[1]), zz),
                        pkmax0(cvtpku(a1[2], a1[3]), zz));
      acc2[rr] = mfma32h(hf.v, w2h.v, acc2[rr]);
      acc2[rr] = mfma32h(hf.v, w2l.v, acc2[rr]);
    }
    w1h0 = nw0; w1h1 = nw1; w2h = n2h; w2l = n2l;
  }

  // ---- epilogue: lane (q,cl) holds MS[h=cl][c=c0+4q+i][r0..r0+7] ----
  u32* ms1u = (u32*)ms1;
#pragma unroll
  for (int rr = 0; rr < 8; rr++) {
    size_t base = ((size_t)(b * 16 + cl) * 512 + (r0 + rr)) * 256 + (c0 >> 1) + q * 2;
    *(uint2*)&ms1u[base] = make_uint2(pk2(acc2[rr][0], acc2[rr][1]),
                                      pk2(acc2[rr][2], acc2[rr][3]));
  }
  u32* ms2u = (u32*)ms2;
#pragma unroll
  for (int i = 0; i < 4; i++) {
    int c = c0 + 4 * q + i;
    u32 o[4];
#pragma unroll
    for (int j = 0; j < 4; j++)
      o[j] = pk2(acc2[2 * j][i], acc2[2 * j + 1][i]);
    size_t base2 = ((size_t)(b * 16 + cl) * 512 + c) * 256 + (r0 >> 1);
    *(uint4*)&ms2u[base2] = make_uint4(o[0], o[1], o[2], o[3]);
  }
}

// ---------------------------------------------------------------------------
// softmax_pv_mf: softmax + PV via MFMA (R9 champion verbatim: XCD-paired bx
// encoding bx%8 = fixtile32%8; in-kernel mask build; ms2 read for dir=1).
// ---------------------------------------------------------------------------
__global__ void __launch_bounds__(256, 4)
softmax_pv_mf(const u16* __restrict__ ms1s, const u16* __restrict__ ms2s,
              const int* __restrict__ mask,
              const u16* __restrict__ vhT1, const u16* __restrict__ vhT2,
              float* __restrict__ o1, float* __restrict__ o2) {
  __shared__ __align__(16) char pbufc[4][8192];     // per-wave P, swizzled
  __shared__ unsigned char maskbytes[8][64];        // bit(cc&7) of byte cc>>3
  __shared__ float sden[4][8];
  int t = threadIdx.x, L = t & 63, w = t >> 6;
  int cl = L & 15, q = L >> 4;
  int bx = blockIdx.x;
  int u  = (bx & 7) + 8 * ((bx >> 3) & 1);   // fix-tile32 (0..15)
  int v  = (bx >> 4) & 3;                    // 8-fix chunk  (0..3)
  int hq = bx >> 6;                          // head quad    (0..3)
  int rt = u * 4 + v;
  int b = blockIdx.y, dir = blockIdx.z;
  int fix0 = rt * 8, h = hq * 4 + w;
  const u16* ms = dir ? ms2s : ms1s;

  // ---- mask build: wave w fills rows f = 2w, 2w+1 (valid bit = 1) ----
  if (dir == 0) {
#pragma unroll
    for (int fo = 0; fo < 2; fo++) {
      int f = 2 * w + fo;
      const int* mr = mask + ((size_t)(b * 512) + fix0 + f) * 512 + 8 * L;
      uint4 m0 = *(const uint4*)mr;
      uint4 m1 = *(const uint4*)(mr + 4);
      u32 bits = (u32)(m0.x != 0)        | ((u32)(m0.y != 0) << 1)
               | ((u32)(m0.z != 0) << 2) | ((u32)(m0.w != 0) << 3)
               | ((u32)(m1.x != 0) << 4) | ((u32)(m1.y != 0) << 5)
               | ((u32)(m1.z != 0) << 6) | ((u32)(m1.w != 0) << 7);
      maskbytes[f][L] = (unsigned char)bits;
    }
  } else {
    u32 b0 = 0, b1 = 0;
#pragma unroll
    for (int j = 0; j < 8; j++) {
      const int* mp = mask + ((size_t)(b * 512) + 8 * L + j) * 512 + fix0 + 2 * w;
      uint2 mv = *(const uint2*)mp;
      b0 |= (u32)(mv.x != 0) << j;
      b1 |= (u32)(mv.y != 0) << j;
    }
    maskbytes[2 * w][L]     = (unsigned char)b0;
    maskbytes[2 * w + 1][L] = (unsigned char)b1;
  }
  __syncthreads();

  // ---- phase 1: softmax over c for 8 fixes of head h ----
  const u16* msbase = ms + ((size_t)((b * 16 + h) * 512) + fix0) * 512 + 8 * L;
  uint4 pre[8];
#pragma unroll
  for (int f = 0; f < 8; f++) pre[f] = *(const uint4*)(msbase + f * 512);

  char* pb = pbufc[w];
#pragma unroll
  for (int f = 0; f < 8; f++) {
    u32 uw[4] = {pre[f].x, pre[f].y, pre[f].z, pre[f].w};
    float lg[8];
#pragma unroll
    for (int j = 0; j < 4; j++) {
      lg[2 * j]     = __uint_as_float(uw[j] << 16);
      lg[2 * j + 1] = __uint_as_float(uw[j] & 0xffff0000u);
    }
    u32 mb = (u32)maskbytes[f][L];
    bool um = (__ballot(mb != 0) != 0ULL);   // fully-masked row => unmask all
    u32 eff = um ? mb : 0xffu;
    float mx = -3.4e38f;
#pragma unroll
    for (int j = 0; j < 8; j++)
      mx = fmaxf(mx, ((eff >> j) & 1) ? lg[j] : -3.4e38f);
    for (int off = 32; off; off >>= 1) mx = fmaxf(mx, __shfl_xor(mx, off));
    float s = 0.f; u32 pw[4];
#pragma unroll
    for (int j = 0; j < 4; j++) {
      float p0 = ((eff >> (2 * j)) & 1)     ? __expf(lg[2 * j]     - mx) : 0.f;
      float p1 = ((eff >> (2 * j + 1)) & 1) ? __expf(lg[2 * j + 1] - mx) : 0.f;
      s += p0 + p1;
      pw[j] = cvtpku(p0, p1);
    }
    for (int off = 32; off; off >>= 1) s += __shfl_xor(s, off);
    if (L == 0) sden[w][f] = s;
    *(uint4*)(pb + f * 1024 + ((16 * L) ^ (f << 4))) = make_uint4(pw[0], pw[1], pw[2], pw[3]);
  }

  // ---- phase 2: PV via MFMA chain over K=512 ----
  const u16* vT = (dir ? vhT1 : vhT2) + ((size_t)(b * 256 + h * 16 + cl) * 512) + 8 * q;
  f32x4 accA; accA[0] = 0.f; accA[1] = 0.f; accA[2] = 0.f; accA[3] = 0.f;
  f32x4 accB = accA;
  int ar = (cl & 7);
#pragma unroll
  for (int kk = 0; kk < 16; kk++) {
    F16x8 pa, vb;
    pa.u = *(const uint4*)(pb + ar * 1024 + (((kk << 6) + (q << 4)) ^ (ar << 4)));
    vb.u = *(const uint4*)(vT + (kk << 5));
    if (kk & 1) accB = mfma32h(pa.v, vb.v, accB);
    else        accA = mfma32h(pa.v, vb.v, accA);
  }

  if (q < 2) {
    float* obuf = dir ? o2 : o1;
#pragma unroll
    for (int i = 0; i < 4; i++) {
      int f = 4 * q + i;
      float inv = 1.f / sden[w][f];
      obuf[((size_t)(b * 512) + fix0 + f) * 256 + h * 16 + cl] = (accA[i] + accB[i]) * inv;
    }
  }
}

// ---------------------------------------------------------------------------
extern "C" void kernel_launch(void* const* d_in, const int* in_sizes, int n_in,
                              void* d_out, int out_size, void* d_ws, size_t ws_size,
                              hipStream_t stream) {
  const float* x1    = (const float*)d_in[0];
  const float* x2    = (const float*)d_in[1];
  const int*   attn  = (const int*)d_in[2];
  const float* cost  = (const float*)d_in[3];
  const float* Wqv1  = (const float*)d_in[4];
  const float* Wkv2  = (const float*)d_in[5];
  const float* W1    = (const float*)d_in[6];
  const float* W2    = (const float*)d_in[7];
  const float* Wout1 = (const float*)d_in[8];
  const float* Wout2 = (const float*)d_in[9];
  float* out = (float*)d_out;

  char* ws = (char*)d_ws;
  uint4* W1F8hi = (uint4*)(ws);                              // 16 KB
  uint4* W1F8lo = (uint4*)(ws + (16 << 10));                 // 16 KB
  uint4* W2F8hi = (uint4*)(ws + (32 << 10));                 //  8 KB
  uint4* W2F8lo = (uint4*)(ws + (40 << 10));                 //  8 KB
  u16*   vhT1 = (u16*)(ws + (64 << 10));                     // 512 KB [b][256 ch][512 r] f16 (v1^T)
  u16*   vhT2 = (u16*)(ws + (64 << 10) + (512 << 10));       // 512 KB [b][256 ch][512 c] f16 (v2^T)
  u16*   ms1 = (u16*)(ws + (64 << 10) + (4 << 20));          //  16 MB [b][h][r][c]
  u16*   ms2 = (u16*)(ws + (64 << 10) + (20 << 20));         //  16 MB [b][h][c][r]
  char*  tail= (ws + (64 << 10) + (36 << 20));
  uint4* QQ4  = (uint4*)(tail);                              //   1 MB
  uint4* KH4  = (uint4*)(tail + (1 << 20));                  // 0.5 MB
  uint4* KL4z = (uint4*)(tail + (1 << 20) + (512 << 10));    //   1 MB
  float* o1  = (float*)(tail + (3 << 20));                   //   1 MB [b][r][256]
  float* o2  = (float*)(tail + (4 << 20));                   //   1 MB [b][c][256]

  gemm_mf_pack<<<dim3(16, 33), 256, 0, stream>>>(x1, Wqv1, vhT1, x2, Wkv2, vhT2,
                                                 W1, W2, QQ4, KH4, KL4z,
                                                 W1F8hi, W1F8lo, W2F8hi, W2F8lo);

  ms_mfma8c<<<dim3(16, 32, 2), 256, 0, stream>>>(QQ4, KH4, KL4z, cost,
                                                 W1F8hi, W1F8lo, W2F8hi, W2F8lo, ms1, ms2);

  softmax_pv_mf<<<dim3(256, 2, 2), 256, 0, stream>>>(ms1, ms2, attn, vhT1, vhT2, o1, o2);

  gemm_mf2t<<<dim3(8, 64), 256, 0, stream>>>(o1, o2, Wout1, Wout2, out);
}